// Round 1
// baseline (733.652 us; speedup 1.0000x reference)
//
#include <hip/hip_runtime.h>

// WindowAttention fused kernel for MI355X (gfx950)
// B_=8192 windows, N=49 tokens, C=192, H=6 heads, dh=32, NW=64 masks.

#define NTOK 49
#define NPAD 64
#define CCH 192
#define NHEAD 6
#define DH 32

typedef __bf16 bf16_t;
typedef bf16_t bf16x8 __attribute__((ext_vector_type(8)));
typedef bf16_t bf16x4 __attribute__((ext_vector_type(4)));
typedef float f32x4 __attribute__((ext_vector_type(4)));

// ws byte offsets
#define WS_WQT   0         // 192*192 bf16 (73728 B)
#define WS_WKVT  73728     // 384*192 bf16 (147456 B)
#define WS_WPT   221184    // 192*192 bf16 (73728 B)
#define WS_BIASG 294912    // 6*49*49 f32 (57624 B)

__global__ void prep_kernel(const float* __restrict__ Wq, const float* __restrict__ Wkv,
                            const float* __restrict__ Wproj, const float* __restrict__ btab,
                            const int* __restrict__ rel,
                            bf16_t* __restrict__ wqt, bf16_t* __restrict__ wkvt,
                            bf16_t* __restrict__ wpt, float* __restrict__ biasg) {
    int i = blockIdx.x * 256 + threadIdx.x;
    if (i < 36864) { int n = i / 192, k = i % 192; wqt[i] = (bf16_t)Wq[k * 192 + n]; }
    int j = i - 36864;
    if (j >= 0 && j < 73728) { int n = j / 192, k = j % 192; wkvt[j] = (bf16_t)Wkv[k * 384 + n]; }
    int p = i - 110592;
    if (p >= 0 && p < 36864) { int n = p / 192, k = p % 192; wpt[p] = (bf16_t)Wproj[k * 192 + n]; }
    int q = i - 147456;
    if (q >= 0 && q < 14406) { int h = q / 2401, rc = q % 2401; biasg[q] = btab[rel[rc] * 6 + h]; }
}

__global__ __launch_bounds__(512) void wattn_kernel(
    const float* __restrict__ xq, const float* __restrict__ mask,
    const float* __restrict__ bq, const float* __restrict__ bkv, const float* __restrict__ bproj,
    const bf16_t* __restrict__ wqt, const bf16_t* __restrict__ wkvt, const bf16_t* __restrict__ wpt,
    const float* __restrict__ biasg, float* __restrict__ out)
{
    // LDS layout (all MFMA-read tiles XOR-swizzled: byte ^= ((row&7)<<4))
    __shared__ __align__(16) unsigned char smem[114688];
    unsigned char* Xs = smem;            // [64][192] bf16, 24576 B; reused as Os in phase 3/4
    unsigned char* Qs = smem + 24576;    // [64][192] bf16
    unsigned char* Ks = smem + 49152;    // [64][192] bf16
    unsigned char* Vt = smem + 73728;    // [192][64] bf16 (transposed V: [channel][token])
    unsigned char* Ps = smem + 98304;    // per-wave [16][64] bf16 (2048 B each, 8 waves)

    const int tid = threadIdx.x;
    const int wid = tid >> 6;
    const int lane = tid & 63;
    const int l15 = lane & 15;
    const int lg = lane >> 4;            // 0..3
    const int b = blockIdx.x;
    const float* xp = xq + (size_t)b * (NTOK * CCH);

    // ---- Phase 1: stage X -> bf16 LDS (rows 49..63 zeroed) ----
    for (int idx = tid; idx < 2352; idx += 512) {   // 49*192/4 float4 loads
        int row = idx / 48;
        int cb = (idx % 48) * 4;
        float4 v = *(const float4*)(xp + row * 192 + cb);
        bf16x4 pk = { (bf16_t)v.x, (bf16_t)v.y, (bf16_t)v.z, (bf16_t)v.w };
        *(bf16x4*)(Xs + row * 384 + ((cb * 2) ^ ((row & 7) << 4))) = pk;
    }
    for (int idx = tid; idx < 720; idx += 512) {    // zero pad rows (15 rows * 384 B)
        *(unsigned long long*)(Xs + 49 * 384 + idx * 8) = 0ULL;
    }
    __syncthreads();

    // ---- Phase 2: QKV projection. 36 n-tiles: 0-11 Q, 12-23 K, 24-35 V ----
    const float SCALE = 0.17677669529663687f;       // dh^-0.5
    for (int nt = wid; nt < 36; nt += 8) {
        int m = nt / 12;
        int ncol = (nt % 12) * 16;
        const bf16_t* WT; const float* bias;
        if (m == 0)      { WT = wqt  + (size_t)ncol * 192;        bias = bq + ncol; }
        else if (m == 1) { WT = wkvt + (size_t)ncol * 192;        bias = bkv + ncol; }
        else             { WT = wkvt + (size_t)(192 + ncol) * 192; bias = bkv + 192 + ncol; }
        bf16x8 bfr[6];
        const bf16_t* wrow = WT + (size_t)l15 * 192 + lg * 8;
#pragma unroll
        for (int ks = 0; ks < 6; ks++) bfr[ks] = *(const bf16x8*)(wrow + ks * 32);
        float bv = bias[l15];
#pragma unroll
        for (int mt = 0; mt < 4; mt++) {
            f32x4 acc = { bv, bv, bv, bv };
#pragma unroll
            for (int ks = 0; ks < 6; ks++) {
                int row = mt * 16 + l15;
                int cb = ks * 32 + lg * 8;
                bf16x8 a = *(const bf16x8*)(Xs + row * 384 + ((cb * 2) ^ ((row & 7) << 4)));
                acc = __builtin_amdgcn_mfma_f32_16x16x32_bf16(a, bfr[ks], acc, 0, 0, 0);
            }
            if (m == 0) {
#pragma unroll
                for (int j = 0; j < 4; j++) acc[j] *= SCALE;
            }
#pragma unroll
            for (int j = 0; j < 4; j++) {
                int col = ncol + l15;
                if (m == 2) {
                    int rr = col;                    // channel row in Vt
                    int tc = mt * 16 + lg * 4 + j;   // token col
                    *(bf16_t*)(Vt + rr * 128 + ((tc * 2) ^ ((rr & 7) << 4))) = (bf16_t)acc[j];
                } else {
                    int rr = mt * 16 + lg * 4 + j;   // token row
                    unsigned char* dst = (m == 0) ? Qs : Ks;
                    *(bf16_t*)(dst + rr * 384 + ((col * 2) ^ ((rr & 7) << 4))) = (bf16_t)acc[j];
                }
            }
        }
    }
    __syncthreads();

    // ---- Phase 3: attention. 24 (head,qtile) units, 3 per wave ----
    const int widx = b & 63;
    const float* maskw = mask + (size_t)widx * 2401;
    unsigned char* Pw = Ps + wid * 2048;

    for (int k3 = 0; k3 < 3; k3++) {
        int u = wid + 8 * k3;
        int h = u >> 2, qt = u & 3;
        // QK^T: A = Q rows (qtile), B = K rows (token tiles), K-dim = dh = 32 (1 step)
        int qrow = qt * 16 + l15;
        int qcb = h * 32 + lg * 8;
        bf16x8 afr = *(const bf16x8*)(Qs + qrow * 384 + ((qcb * 2) ^ ((qrow & 7) << 4)));
        f32x4 s[4];
#pragma unroll
        for (int f = 0; f < 4; f++) {
            int krow = f * 16 + l15;
            bf16x8 kfr = *(const bf16x8*)(Ks + krow * 384 + ((qcb * 2) ^ ((krow & 7) << 4)));
            f32x4 z = { 0.f, 0.f, 0.f, 0.f };
            s[f] = __builtin_amdgcn_mfma_f32_16x16x32_bf16(afr, kfr, z, 0, 0, 0);
        }
        // bias + mask; pad cols -> -inf
        const float* bgh = biasg + h * 2401;
#pragma unroll
        for (int f = 0; f < 4; f++) {
            int c = f * 16 + l15;
#pragma unroll
            for (int j = 0; j < 4; j++) {
                int r = qt * 16 + lg * 4 + j;
                if (c >= 49) s[f][j] = -1e30f;
                else if (r < 49) s[f][j] += bgh[r * 49 + c] + maskw[r * 49 + c];
            }
        }
        // softmax per row (rows live in 16-lane groups; cols across lanes+frags)
        float mx[4], rs[4];
#pragma unroll
        for (int j = 0; j < 4; j++) {
            float m0 = fmaxf(fmaxf(s[0][j], s[1][j]), fmaxf(s[2][j], s[3][j]));
#pragma unroll
            for (int d = 1; d < 16; d <<= 1) m0 = fmaxf(m0, __shfl_xor(m0, d, 16));
            mx[j] = m0;
        }
#pragma unroll
        for (int j = 0; j < 4; j++) {
            float t = 0.f;
#pragma unroll
            for (int f = 0; f < 4; f++) { s[f][j] = __expf(s[f][j] - mx[j]); t += s[f][j]; }
#pragma unroll
            for (int d = 1; d < 16; d <<= 1) t += __shfl_xor(t, d, 16);
            rs[j] = 1.0f / t;
        }
        // write normalized P (bf16) to per-wave LDS
#pragma unroll
        for (int f = 0; f < 4; f++) {
            int c = f * 16 + l15;
#pragma unroll
            for (int j = 0; j < 4; j++) {
                int rr = lg * 4 + j;
                *(bf16_t*)(Pw + rr * 128 + ((c * 2) ^ ((rr & 7) << 4))) = (bf16_t)(s[f][j] * rs[j]);
            }
        }
        __threadfence_block();   // order P writes before P reads (same wave, cross-type LDS access)
        // PV: A = P [16 q][64 tok], B = Vt [d][tok]
        bf16x8 pa[2];
#pragma unroll
        for (int ks = 0; ks < 2; ks++) {
            int pcb = ks * 32 + lg * 8;
            pa[ks] = *(const bf16x8*)(Pw + l15 * 128 + ((pcb * 2) ^ ((l15 & 7) << 4)));
        }
#pragma unroll
        for (int dt = 0; dt < 2; dt++) {
            f32x4 acc = { 0.f, 0.f, 0.f, 0.f };
#pragma unroll
            for (int ks = 0; ks < 2; ks++) {
                int vr = h * 32 + dt * 16 + l15;
                int vcb = ks * 32 + lg * 8;
                bf16x8 vfr = *(const bf16x8*)(Vt + vr * 128 + ((vcb * 2) ^ ((vr & 7) << 4)));
                acc = __builtin_amdgcn_mfma_f32_16x16x32_bf16(pa[ks], vfr, acc, 0, 0, 0);
            }
#pragma unroll
            for (int j = 0; j < 4; j++) {
                int orow = qt * 16 + lg * 4 + j;
                int ocol = h * 32 + dt * 16 + l15;
                *(bf16_t*)(Xs + orow * 384 + ((ocol * 2) ^ ((orow & 7) << 4))) = (bf16_t)acc[j];
            }
        }
    }
    __syncthreads();

    // ---- Phase 4: out projection: OUT = O @ WprojT + bproj ----
    float* op = out + (size_t)b * (NTOK * CCH);
    for (int nt = wid; nt < 12; nt += 8) {
        int ncol = nt * 16;
        bf16x8 bfr[6];
        const bf16_t* wrow = wpt + (size_t)(ncol + l15) * 192 + lg * 8;
#pragma unroll
        for (int ks = 0; ks < 6; ks++) bfr[ks] = *(const bf16x8*)(wrow + ks * 32);
        float bv = bproj[ncol + l15];
#pragma unroll
        for (int mt = 0; mt < 4; mt++) {
            f32x4 acc = { bv, bv, bv, bv };
#pragma unroll
            for (int ks = 0; ks < 6; ks++) {
                int row = mt * 16 + l15;
                int cb = ks * 32 + lg * 8;
                bf16x8 a = *(const bf16x8*)(Xs + row * 384 + ((cb * 2) ^ ((row & 7) << 4)));
                acc = __builtin_amdgcn_mfma_f32_16x16x32_bf16(a, bfr[ks], acc, 0, 0, 0);
            }
#pragma unroll
            for (int j = 0; j < 4; j++) {
                int r = mt * 16 + lg * 4 + j;
                if (r < 49) op[r * 192 + ncol + l15] = acc[j];
            }
        }
    }
}

extern "C" void kernel_launch(void* const* d_in, const int* in_sizes, int n_in,
                              void* d_out, int out_size, void* d_ws, size_t ws_size,
                              hipStream_t stream) {
    const float* xq    = (const float*)d_in[0];
    const float* mask  = (const float*)d_in[1];
    const float* Wq    = (const float*)d_in[2];
    const float* bq    = (const float*)d_in[3];
    const float* Wkv   = (const float*)d_in[4];
    const float* bkv   = (const float*)d_in[5];
    const float* Wproj = (const float*)d_in[6];
    const float* bproj = (const float*)d_in[7];
    const float* btab  = (const float*)d_in[8];
    const int*   rel   = (const int*)d_in[9];
    float* out = (float*)d_out;

    char* ws = (char*)d_ws;
    bf16_t* wqt   = (bf16_t*)(ws + WS_WQT);
    bf16_t* wkvt  = (bf16_t*)(ws + WS_WKVT);
    bf16_t* wpt   = (bf16_t*)(ws + WS_WPT);
    float*  biasg = (float*)(ws + WS_BIASG);

    prep_kernel<<<633, 256, 0, stream>>>(Wq, Wkv, Wproj, btab, rel, wqt, wkvt, wpt, biasg);
    wattn_kernel<<<8192, 512, 0, stream>>>(xq, mask, bq, bkv, bproj, wqt, wkvt, wpt, biasg, out);
}

// Round 2
// 642.424 us; speedup vs baseline: 1.1420x; 1.1420x over previous
//
#include <hip/hip_runtime.h>

// WindowAttention fused kernel for MI355X (gfx950) — round 2
// B_=8192 windows, N=49 tokens, C=192, H=6 heads, dh=32, NW=64 masks.
// One block = one window, 1024 threads (16 waves), 128KB LDS.

#define NTOK 49
#define CCH 192

typedef __bf16 bf16_t;
typedef bf16_t bf16x8 __attribute__((ext_vector_type(8)));
typedef bf16_t bf16x4 __attribute__((ext_vector_type(4)));
typedef float f32x4 __attribute__((ext_vector_type(4)));

// ws byte offsets
#define WS_WQT   0         // 192*192 bf16, Q-weights pre-scaled (73728 B)
#define WS_WKVT  73728     // 384*192 bf16 (147456 B)
#define WS_WPT   221184    // 192*192 bf16 (73728 B)
#define WS_BQS   294912    // 192 f32 pre-scaled q-bias (768 B)
#define WS_TBL   295680    // bias/mask tables (mode-dependent)

#define SWZ(row, off) ((off) ^ (((row) & 7) << 4))

__global__ void prep_kernel(const float* __restrict__ Wq, const float* __restrict__ bq,
                            const float* __restrict__ Wkv, const float* __restrict__ Wproj,
                            const float* __restrict__ btab, const int* __restrict__ rel,
                            const float* __restrict__ mask,
                            bf16_t* __restrict__ wqt, bf16_t* __restrict__ wkvt,
                            bf16_t* __restrict__ wpt, float* __restrict__ bqs,
                            float* __restrict__ tbl, int mode) {
    const float SC = 0.17677669529663687f;
    long i = (long)blockIdx.x * 256 + threadIdx.x;
    if (i < 36864) { int n = i / 192, k = i % 192; wqt[i] = (bf16_t)(Wq[k * 192 + n] * SC); return; }
    i -= 36864;
    if (i < 73728) { int n = i / 192, k = i % 192; wkvt[i] = (bf16_t)Wkv[k * 384 + n]; return; }
    i -= 73728;
    if (i < 36864) { int n = i / 192, k = i % 192; wpt[i] = (bf16_t)Wproj[k * 192 + n]; return; }
    i -= 36864;
    if (i < 192) { bqs[i] = bq[i] * SC; return; }
    i -= 192;
    if (mode == 0) {            // presummed bm [64][6][49][52]
        if (i < 979072) {
            int c = i % 52; long r = i / 52; int q = r % 49; r /= 49; int h = r % 6; int w = r / 6;
            tbl[i] = (c < 49) ? (btab[rel[q * 49 + c] * 6 + h] + mask[(size_t)w * 2401 + q * 49 + c]) : 0.f;
        }
    } else if (mode == 1) {     // biasp [6][49][52] + maskp [64][49][52]
        if (i < 15288) { int c = i % 52; int r = i / 52; int q = r % 49; int h = r / 49;
            tbl[i] = (c < 49) ? btab[rel[q * 49 + c] * 6 + h] : 0.f; return; }
        i -= 15288;
        if (i < 163072) { int c = i % 52; long r = i / 52; int q = r % 49; int w = r / 49;
            tbl[15288 + i] = (c < 49) ? mask[(size_t)w * 2401 + q * 49 + c] : 0.f; }
    } else {                    // biasg [6][49][49] (scalar fallback)
        if (i < 14406) { int h = i / 2401, rc = i % 2401; tbl[i] = btab[rel[rc] * 6 + h]; }
    }
}

__global__ __launch_bounds__(1024, 4) void wattn_kernel(
    const float* __restrict__ xq, const float* __restrict__ mask,
    const float* __restrict__ bkv, const float* __restrict__ bproj,
    const bf16_t* __restrict__ wqt, const bf16_t* __restrict__ wkvt, const bf16_t* __restrict__ wpt,
    const float* __restrict__ bqs, const float* __restrict__ tbl,
    float* __restrict__ out, int mode)
{
    __shared__ __align__(16) unsigned char smem[131072];
    unsigned char* XsO = smem;           // [64][384B] X bf16; reused as O in phase 3/4
    unsigned char* Qs  = smem + 24576;   // [64][384B]
    unsigned char* Ks  = smem + 49152;   // [64][384B]
    unsigned char* Vt  = smem + 73728;   // [192][128B] (V transposed: [chan][token])
    unsigned char* Ps  = smem + 98304;   // per-wave [16][128B], 2KB x 16 waves

    const int tid = threadIdx.x;
    const int wid = tid >> 6;
    const int lane = tid & 63;
    const int l15 = lane & 15;
    const int lg = lane >> 4;            // 0..3
    const int b = blockIdx.x;
    const float* xp = xq + (size_t)b * (NTOK * CCH);

    // ---- Phase 1: stage X -> bf16 LDS (rows 49..63 zeroed) ----
    for (int idx = tid; idx < 2352; idx += 1024) {   // 49 rows * 48 float4
        int row = idx / 48;
        int c4 = idx % 48;
        float4 v = *(const float4*)(xp + row * 192 + c4 * 4);
        bf16x4 pk = { (bf16_t)v.x, (bf16_t)v.y, (bf16_t)v.z, (bf16_t)v.w };
        *(bf16x4*)(XsO + row * 384 + SWZ(row, c4 * 8)) = pk;
    }
    if (tid < 720) *(unsigned long long*)(XsO + 49 * 384 + tid * 8) = 0ULL;
    __syncthreads();

    // ---- Phase 2: QKV projection. 144 units = 36 ntiles x 4 mtiles; 9 per wave ----
    {
        bf16x8 bfr[6];
        float4 bias4;
        float bv = 0.f;
        int prev_ut = -1;
        for (int u = 9 * wid; u < 9 * wid + 9; ++u) {
            int ut = u >> 2, mt = u & 3;
            bool isV = (ut >= 24);
            if (ut != prev_ut) {
                prev_ut = ut;
                const bf16_t* wrow;
                if (ut < 12)      wrow = wqt  + (size_t)(ut * 16 + l15) * 192;
                else if (ut < 24) wrow = wkvt + (size_t)((ut - 12) * 16 + l15) * 192;
                else              wrow = wkvt + (size_t)(192 + (ut - 24) * 16 + l15) * 192;
#pragma unroll
                for (int ks = 0; ks < 6; ks++) bfr[ks] = *(const bf16x8*)(wrow + ks * 32 + lg * 8);
                if (!isV) {
                    const float* bp = (ut < 12) ? (bqs + ut * 16) : (bkv + (ut - 12) * 16);
                    bias4 = *(const float4*)(bp + lg * 4);
                } else {
                    bv = bkv[192 + (ut - 24) * 16 + l15];
                }
            }
            int xrow = mt * 16 + l15;
            bf16x8 xf[6];
#pragma unroll
            for (int ks = 0; ks < 6; ks++)
                xf[ks] = *(const bf16x8*)(XsO + xrow * 384 + SWZ(xrow, ks * 64 + lg * 16));
            if (!isV) {
                // swapped: D[outchan][token] -> lane holds 4 consecutive outchans of one token
                f32x4 acc = { bias4.x, bias4.y, bias4.z, bias4.w };
#pragma unroll
                for (int ks = 0; ks < 6; ks++)
                    acc = __builtin_amdgcn_mfma_f32_16x16x32_bf16(bfr[ks], xf[ks], acc, 0, 0, 0);
                int ncol = (ut < 12 ? ut : ut - 12) * 16;
                unsigned char* dst = (ut < 12) ? Qs : Ks;
                bf16x4 pk = { (bf16_t)acc[0], (bf16_t)acc[1], (bf16_t)acc[2], (bf16_t)acc[3] };
                int trow = mt * 16 + l15;
                *(bf16x4*)(dst + trow * 384 + SWZ(trow, ncol * 2 + lg * 8)) = pk;
            } else {
                // normal: D[token][chan] -> lane holds 4 consecutive tokens of one chan
                f32x4 acc = { bv, bv, bv, bv };
#pragma unroll
                for (int ks = 0; ks < 6; ks++)
                    acc = __builtin_amdgcn_mfma_f32_16x16x32_bf16(xf[ks], bfr[ks], acc, 0, 0, 0);
                int crow = (ut - 24) * 16 + l15;
                bf16x4 pk = { (bf16_t)acc[0], (bf16_t)acc[1], (bf16_t)acc[2], (bf16_t)acc[3] };
                *(bf16x4*)(Vt + crow * 128 + SWZ(crow, mt * 32 + lg * 8)) = pk;
            }
        }
    }
    __syncthreads();

    // ---- Phase 3: attention, 24 (head,qtile) units over 16 waves ----
    const int widx = b & 63;
    unsigned char* Pw = Ps + wid * 2048;
    for (int u = wid; u < 24; u += 16) {
        int h = u >> 2, qt = u & 3;
        int cb = h * 64 + lg * 16;   // byte offset of chan chunk h*32 + lg*8
        int qrow = qt * 16 + l15;
        bf16x8 qfr = *(const bf16x8*)(Qs + qrow * 384 + SWZ(qrow, cb));
        f32x4 s[4];
#pragma unroll
        for (int f = 0; f < 4; f++) {
            int kr = f * 16 + l15;
            bf16x8 kfr = *(const bf16x8*)(Ks + kr * 384 + SWZ(kr, cb));
            f32x4 z = { 0.f, 0.f, 0.f, 0.f };
            s[f] = __builtin_amdgcn_mfma_f32_16x16x32_bf16(kfr, qfr, z, 0, 0, 0);  // S^T tile
        }
        // lane holds S[q=qt*16+l15][k = f*16 + lg*4 + j]
        int q = qt * 16 + l15;
        bool qok = (q < 49);
#pragma unroll
        for (int f = 0; f < 4; f++) {
            int kb = f * 16 + lg * 4;
            float4 a = { 0.f, 0.f, 0.f, 0.f };
            if (qok && kb < 49) {
                if (mode == 0) {
                    a = *(const float4*)(tbl + (((size_t)(widx * 6 + h) * 49 + q) * 52 + kb));
                } else if (mode == 1) {
                    float4 b1 = *(const float4*)(tbl + ((size_t)(h * 49 + q) * 52 + kb));
                    float4 m1 = *(const float4*)(tbl + 15288 + (((size_t)widx * 49 + q) * 52 + kb));
                    a.x = b1.x + m1.x; a.y = b1.y + m1.y; a.z = b1.z + m1.z; a.w = b1.w + m1.w;
                }
            }
#pragma unroll
            for (int j = 0; j < 4; j++) {
                int k = kb + j;
                float av = (j == 0) ? a.x : (j == 1) ? a.y : (j == 2) ? a.z : a.w;
                if (mode == 2) {
                    av = 0.f;
                    if (qok && k < 49)
                        av = tbl[h * 2401 + q * 49 + k] + mask[(size_t)widx * 2401 + q * 49 + k];
                }
                if (k >= 49) s[f][j] = -1e30f;
                else if (qok) s[f][j] += av;
            }
        }
        // softmax over k (16 in-lane + reduce across lg groups)
        float m = -1e30f;
#pragma unroll
        for (int f = 0; f < 4; f++)
#pragma unroll
            for (int j = 0; j < 4; j++) m = fmaxf(m, s[f][j]);
        m = fmaxf(m, __shfl_xor(m, 16));
        m = fmaxf(m, __shfl_xor(m, 32));
        float t = 0.f;
#pragma unroll
        for (int f = 0; f < 4; f++)
#pragma unroll
            for (int j = 0; j < 4; j++) { s[f][j] = __expf(s[f][j] - m); t += s[f][j]; }
        t += __shfl_xor(t, 16);
        t += __shfl_xor(t, 32);
        float inv = 1.0f / t;
        // P store: row q-local = l15, 4 consecutive k per f
#pragma unroll
        for (int f = 0; f < 4; f++) {
            bf16x4 pk = { (bf16_t)(s[f][0] * inv), (bf16_t)(s[f][1] * inv),
                          (bf16_t)(s[f][2] * inv), (bf16_t)(s[f][3] * inv) };
            *(bf16x4*)(Pw + l15 * 128 + SWZ(l15, f * 32 + lg * 8)) = pk;
        }
        __threadfence_block();
        bf16x8 pa[2];
#pragma unroll
        for (int ks = 0; ks < 2; ks++)
            pa[ks] = *(const bf16x8*)(Pw + l15 * 128 + SWZ(l15, ks * 64 + lg * 16));
        // PV swapped: D[chan][q] -> lane holds 4 consecutive chans of one q
#pragma unroll
        for (int dt = 0; dt < 2; dt++) {
            f32x4 acc = { 0.f, 0.f, 0.f, 0.f };
#pragma unroll
            for (int ks = 0; ks < 2; ks++) {
                int vr = h * 32 + dt * 16 + l15;
                bf16x8 vfr = *(const bf16x8*)(Vt + vr * 128 + SWZ(vr, ks * 64 + lg * 16));
                acc = __builtin_amdgcn_mfma_f32_16x16x32_bf16(vfr, pa[ks], acc, 0, 0, 0);
            }
            int orow = qt * 16 + l15;
            bf16x4 pk = { (bf16_t)acc[0], (bf16_t)acc[1], (bf16_t)acc[2], (bf16_t)acc[3] };
            *(bf16x4*)(XsO + orow * 384 + SWZ(orow, h * 64 + dt * 32 + lg * 8)) = pk;
        }
    }
    __syncthreads();

    // ---- Phase 4: out projection, 48 units = 12 ntiles x 4 mtiles; 3 per wave ----
    {
        float* op = out + (size_t)b * (NTOK * CCH);
        bf16x8 bfr[6];
        float4 bias4 = { 0.f, 0.f, 0.f, 0.f };
        int prev_nt = -1;
        for (int u = 3 * wid; u < 3 * wid + 3; ++u) {
            int nt = u >> 2, mt = u & 3;
            if (nt != prev_nt) {
                prev_nt = nt;
                const bf16_t* wrow = wpt + (size_t)(nt * 16 + l15) * 192;
#pragma unroll
                for (int ks = 0; ks < 6; ks++) bfr[ks] = *(const bf16x8*)(wrow + ks * 32 + lg * 8);
                bias4 = *(const float4*)(bproj + nt * 16 + lg * 4);
            }
            int orow = mt * 16 + l15;
            f32x4 acc = { bias4.x, bias4.y, bias4.z, bias4.w };
#pragma unroll
            for (int ks = 0; ks < 6; ks++) {
                bf16x8 of = *(const bf16x8*)(XsO + orow * 384 + SWZ(orow, ks * 64 + lg * 16));
                acc = __builtin_amdgcn_mfma_f32_16x16x32_bf16(bfr[ks], of, acc, 0, 0, 0);
            }
            if (orow < 49) {
                float4 st = { acc[0], acc[1], acc[2], acc[3] };
                *(float4*)(op + orow * 192 + nt * 16 + lg * 4) = st;
            }
        }
    }
}

extern "C" void kernel_launch(void* const* d_in, const int* in_sizes, int n_in,
                              void* d_out, int out_size, void* d_ws, size_t ws_size,
                              hipStream_t stream) {
    const float* xq    = (const float*)d_in[0];
    const float* mask  = (const float*)d_in[1];
    const float* Wq    = (const float*)d_in[2];
    const float* bq    = (const float*)d_in[3];
    const float* Wkv   = (const float*)d_in[4];
    const float* bkv   = (const float*)d_in[5];
    const float* Wproj = (const float*)d_in[6];
    const float* bproj = (const float*)d_in[7];
    const float* btab  = (const float*)d_in[8];
    const int*   rel   = (const int*)d_in[9];
    float* out = (float*)d_out;

    char* ws = (char*)d_ws;
    bf16_t* wqt  = (bf16_t*)(ws + WS_WQT);
    bf16_t* wkvt = (bf16_t*)(ws + WS_WKVT);
    bf16_t* wpt  = (bf16_t*)(ws + WS_WPT);
    float*  bqs  = (float*)(ws + WS_BQS);
    float*  tbl  = (float*)(ws + WS_TBL);

    // pick bias/mask table mode by available workspace
    size_t need0 = (size_t)WS_TBL + 979072u * 4u;   // presummed [64][6][49][52]
    size_t need1 = (size_t)WS_TBL + 178360u * 4u;   // padded bias + padded mask
    int mode = (ws_size >= need0) ? 0 : (ws_size >= need1 ? 1 : 2);

    long prep_elems = 147648L + (mode == 0 ? 979072L : (mode == 1 ? 178360L : 14406L));
    int prep_blocks = (int)((prep_elems + 255) / 256);
    prep_kernel<<<prep_blocks, 256, 0, stream>>>(Wq, bq, Wkv, Wproj, btab, rel, mask,
                                                 wqt, wkvt, wpt, bqs, tbl, mode);
    wattn_kernel<<<8192, 1024, 0, stream>>>(xq, mask, bkv, bproj, wqt, wkvt, wpt,
                                            bqs, tbl, out, mode);
}